// Round 4
// baseline (661.823 us; speedup 1.0000x reference)
//
#include <hip/hip_runtime.h>
#include <hip/hip_bf16.h>

#define T_TOK 4096
#define DM 1024
#define DH 4096
#define NE 8
#define NSLOT (T_TOK * 2)
#define WELEMS ((size_t)NE * DH * DM)

typedef __attribute__((ext_vector_type(4))) float fl4;
typedef __attribute__((ext_vector_type(8))) short sh8;
typedef __attribute__((ext_vector_type(8))) unsigned short us8;
typedef unsigned short u16;

__device__ __forceinline__ u16 f2bf(float f) {
  __hip_bfloat16 h = __float2bfloat16(f);
  return __builtin_bit_cast(u16, h);
}

__device__ __forceinline__ float gelu_tanh(float x) {
  float x3 = x * x * x;
  float u = 0.7978845608028654f * (x + 0.044715f * x3);
  return 0.5f * x * (1.0f + tanhf(u));
}

__device__ __forceinline__ void gload_lds16(const void* g, void* l) {
  __builtin_amdgcn_global_load_lds(
      (const __attribute__((address_space(1))) unsigned int*)g,
      (__attribute__((address_space(3))) unsigned int*)l, 16, 0, 0);
}

template <int N>
__device__ __forceinline__ void wait_vmcnt() {
  if constexpr (N == 0) asm volatile("s_waitcnt vmcnt(0)" ::: "memory");
  else if constexpr (N == 3) asm volatile("s_waitcnt vmcnt(3)" ::: "memory");
  else if constexpr (N == 4) asm volatile("s_waitcnt vmcnt(4)" ::: "memory");
}

// ---------------- weight fp32 -> bf16 ----------------
__global__ __launch_bounds__(256) void wconv_kernel(
    const float* __restrict__ w1, const float* __restrict__ w2,
    u16* __restrict__ w1b, u16* __restrict__ w2b) {
  size_t stride = (size_t)gridDim.x * 256 * 8;
  for (size_t i = ((size_t)blockIdx.x * 256 + threadIdx.x) * 8; i < WELEMS; i += stride) {
    fl4 a0 = *(const fl4*)(w1 + i);
    fl4 a1 = *(const fl4*)(w1 + i + 4);
    fl4 b0 = *(const fl4*)(w2 + i);
    fl4 b1 = *(const fl4*)(w2 + i + 4);
    us8 oa, ob;
#pragma unroll
    for (int j = 0; j < 4; j++) {
      oa[j] = f2bf(a0[j]); oa[j + 4] = f2bf(a1[j]);
      ob[j] = f2bf(b0[j]); ob[j + 4] = f2bf(b1[j]);
    }
    *(us8*)(w1b + i) = oa;
    *(us8*)(w2b + i) = ob;
  }
}

// ---------------- router ----------------
__global__ __launch_bounds__(256) void router_kernel(
    const float* __restrict__ x, const float* __restrict__ rw,
    u16* __restrict__ xbf, int* __restrict__ tok_e, float* __restrict__ tok_w,
    int* __restrict__ ctl) {
  int tid = threadIdx.x;
  int wv = tid >> 6, lane = tid & 63;
  int t = blockIdx.x * 4 + wv;
  if (t >= T_TOK) return;

  const float* xp = x + (size_t)t * DM + lane * 16;
  fl4 xq[4];
#pragma unroll
  for (int i = 0; i < 4; i++) xq[i] = *(const fl4*)(xp + i * 4);

  float acc8[NE];
#pragma unroll
  for (int e = 0; e < NE; e++) {
    const float* wp = rw + (size_t)e * DM + lane * 16;
    float s = 0.f;
#pragma unroll
    for (int i = 0; i < 4; i++) {
      fl4 w4 = *(const fl4*)(wp + i * 4);
      s += xq[i][0] * w4[0] + xq[i][1] * w4[1] + xq[i][2] * w4[2] + xq[i][3] * w4[3];
    }
    acc8[e] = s;
  }
  us8 h0, h1;
#pragma unroll
  for (int i = 0; i < 8; i++) {
    h0[i] = f2bf(xq[i >> 2][i & 3]);
    h1[i] = f2bf(xq[2 + (i >> 2)][i & 3]);
  }
  *(us8*)(xbf + (size_t)t * DM + lane * 16) = h0;
  *(us8*)(xbf + (size_t)t * DM + lane * 16 + 8) = h1;

#pragma unroll
  for (int e = 0; e < NE; e++) {
#pragma unroll
    for (int off = 32; off > 0; off >>= 1) acc8[e] += __shfl_xor(acc8[e], off);
  }

  if (lane == 0) {
    float v1 = -1e30f, v2 = -1e30f;
    int i1 = 0, i2 = 0;
#pragma unroll
    for (int e = 0; e < NE; e++) {
      float v = acc8[e];
      if (v > v1) { v2 = v1; i2 = i1; v1 = v; i1 = e; }
      else if (v > v2) { v2 = v; i2 = e; }
    }
    float ex = expf(v2 - v1);
    float s = 1.0f + ex;
    tok_e[t * 2] = i1; tok_e[t * 2 + 1] = i2;
    tok_w[t * 2] = 1.0f / s; tok_w[t * 2 + 1] = ex / s;
    atomicAdd(&ctl[i1], 1);
    atomicAdd(&ctl[i2], 1);
  }
}

__global__ void scan_kernel(int* __restrict__ ctl) {
  if (threadIdx.x == 0 && blockIdx.x == 0) {
    int s = 0;
    for (int e = 0; e < NE; e++) {
      int c = ctl[e];
      ctl[16 + e] = s;
      ctl[8 + e] = s;
      s += c;
    }
  }
}

__global__ __launch_bounds__(256) void assign_kernel(
    const int* __restrict__ tok_e, const float* __restrict__ tok_w,
    int* __restrict__ ctl, int* __restrict__ tok_map, float* __restrict__ pair_w) {
  int t = blockIdx.x * 256 + threadIdx.x;
  if (t < T_TOK) {
#pragma unroll
    for (int k = 0; k < 2; k++) {
      int e = tok_e[t * 2 + k];
      int slot = atomicAdd(&ctl[8 + e], 1);
      tok_map[slot] = t;
      pair_w[slot] = tok_w[t * 2 + k];
    }
  }
}

// ---------------- 8-phase grouped GEMM: BM=256, BK=64, 8 waves ----------------
// RACE-FIX (round 4): fragment mapping is half-partitioned so phase (MH,NH)
// reads ONLY the matching tile halves:
//   A row = MH*128 + wr*64 + m*16 + l15   (q0/q1 read A-lo only, q2/q3 A-hi)
//   B col = NH*(BN/2) + wc*(BN/8) + n*16 + l15 (NH=0 phases read B-lo only)
// Stage targets per phase never overlap any region read in-or-after that phase
// within the current tile: q0:A-hi(t+1)->buf^1, q1:B-hi(t+1)->buf^1,
// q2:A-lo(t+2)->buf (A-lo last read in q0, before q1-end barrier),
// q3:B-lo(t+2)->buf (B-lo last read in q2, before q2-end barrier).
// Counted vmcnt(VMC) once per K-tile (never 0 in loop).
template <bool FC1, int BN>
__global__ __launch_bounds__(512, 2) void moe_gemm8(
    const u16* __restrict__ Ab, const u16* __restrict__ W,
    const float* __restrict__ bias, u16* __restrict__ Hout,
    float* __restrict__ Out, const int* __restrict__ tok_map,
    const float* __restrict__ pair_w, const int* __restrict__ ctl) {
  constexpr int BM = 256;
  constexpr int KTOT = FC1 ? DM : DH;
  constexpr int NTOT = FC1 ? DH : DM;
  constexpr int NT = NTOT / BN;
  constexpr int MT = NSLOT / BM;   // 32
  constexpr int NK = KTOT / 64;
  constexpr int NHF = BN / 128;    // B frags per phase: 2 (fc1) / 1 (fc2)
  constexpr int N_R = 2 * NHF;     // total B frags: 4 / 2
  constexpr int LPH_B = BN / 128;  // B gloads per stage
  constexpr int VMC = 2 + LPH_B;
  constexpr int ATS = BM * 128;    // 32 KB per A buffer
  constexpr int BTS = BN * 128;
  constexpr int BOFF = 2 * ATS;
  constexpr int NWG = NE * MT * NT;

  __shared__ char lds[2 * ATS + 2 * BTS];

  int bid = blockIdx.x;
  int swz = (bid & 7) * (NWG / 8) + (bid >> 3);
  int mt = swz % MT;
  int tmp = swz / MT;
  int nt = tmp % NT;
  int e = tmp / NT;

  int base = ctl[16 + e], cnt = ctl[e];
  if (mt * BM >= cnt) return;

  int tid = threadIdx.x;
  int wv = tid >> 6, lane = tid & 63;
  int wr = wv >> 2, wc = wv & 3;
  int l15 = lane & 15, kc = lane >> 4;
  int kcs = (kc ^ (((l15 >> 2) & 1) << 1)) * 16;  // read-side swizzle

  // staging source pointers (write-side inverse swizzle folded into global src)
  int c16 = (lane & 7) ^ (((lane >> 5) & 1) << 1);
  const u16* aptr[2][2];
#pragma unroll
  for (int h = 0; h < 2; h++)
#pragma unroll
    for (int j = 0; j < 2; j++) {
      int rl = (wv * 2 + j) * 8 + (lane >> 3);
      int slot = base + mt * BM + h * 128 + rl;
      if (slot >= NSLOT) slot = NSLOT - 1;  // clamp: garbage rows masked on store
      size_t arow = FC1 ? (size_t)tok_map[slot] : (size_t)slot;
      aptr[h][j] = Ab + arow * KTOT + c16 * 8;
    }
  const u16* bptr[2][LPH_B];
#pragma unroll
  for (int h = 0; h < 2; h++)
#pragma unroll
    for (int j = 0; j < LPH_B; j++) {
      int rl = (wv * LPH_B + j) * 8 + (lane >> 3);
      int wrow = nt * BN + h * (BN / 2) + rl;
      bptr[h][j] = W + ((size_t)e * NTOT + wrow) * KTOT + c16 * 8;
    }

#define STAGE_A(H, BUFW, KT)                                                     \
  { _Pragma("unroll") for (int j = 0; j < 2; j++)                                \
      gload_lds16(aptr[H][j] + (KT) * 64,                                        \
                  lds + (BUFW) * ATS + (H) * (ATS / 2) + (wv * 2 + j) * 1024); }
#define STAGE_B(H, BUFW, KT)                                                     \
  { _Pragma("unroll") for (int j = 0; j < LPH_B; j++)                            \
      gload_lds16(bptr[H][j] + (KT) * 64,                                        \
                  lds + BOFF + (BUFW) * BTS + (H) * (BTS / 2) +                  \
                      (wv * LPH_B + j) * 1024); }

  fl4 acc[8][N_R];
#pragma unroll
  for (int m = 0; m < 8; m++)
#pragma unroll
    for (int n = 0; n < N_R; n++) acc[m][n] = (fl4){0.f, 0.f, 0.f, 0.f};

  sh8 afr[4][2];

#define PHASE(MH, NH, READA, STAGE_STMT, LAST)                                   \
  {                                                                              \
    if (READA) {                                                                 \
      _Pragma("unroll") for (int m = 0; m < 4; m++)                              \
      _Pragma("unroll") for (int kk = 0; kk < 2; kk++)                           \
        afr[m][kk] = *(const sh8*)(lds + bufr * ATS +                            \
            (((MH) * 128 + wr * 64 + m * 16 + l15) * 128 + kk * 64 + kcs));      \
    }                                                                            \
    sh8 bfr[NHF][2];                                                             \
    _Pragma("unroll") for (int n = 0; n < NHF; n++)                              \
    _Pragma("unroll") for (int kk = 0; kk < 2; kk++)                             \
      bfr[n][kk] = *(const sh8*)(lds + BOFF + bufr * BTS +                       \
          (((NH) * (BN / 2) + wc * (BN / 8) + n * 16 + l15) * 128 +              \
           kk * 64 + kcs));                                                      \
    STAGE_STMT;                                                                  \
    __builtin_amdgcn_s_barrier();                                                \
    asm volatile("s_waitcnt lgkmcnt(0)" ::: "memory");                           \
    __builtin_amdgcn_sched_barrier(0);                                           \
    __builtin_amdgcn_s_setprio(1);                                               \
    _Pragma("unroll") for (int m = 0; m < 4; m++)                                \
    _Pragma("unroll") for (int n = 0; n < NHF; n++)                              \
    _Pragma("unroll") for (int kk = 0; kk < 2; kk++)                             \
      acc[(MH) * 4 + m][(NH) * NHF + n] = __builtin_amdgcn_mfma_f32_16x16x32_bf16( \
          afr[m][kk], bfr[n][kk], acc[(MH) * 4 + m][(NH) * NHF + n], 0, 0, 0);   \
    __builtin_amdgcn_s_setprio(0);                                               \
    if (LAST) wait_vmcnt<VMC>();                                                 \
    __builtin_amdgcn_s_barrier();                                                \
  }

  // prologue: tile0 all 4 halves + tile1 A-lo/B-lo; last 2 stages stay in flight
  STAGE_A(0, 0, 0); STAGE_B(0, 0, 0);
  STAGE_A(1, 0, 0); STAGE_B(1, 0, 0);
  STAGE_A(0, 1, 1); STAGE_B(0, 1, 1);
  wait_vmcnt<VMC>();
  __builtin_amdgcn_s_barrier();

  for (int t = 0; t < NK; ++t) {
    int bufr = t & 1;
    int k1 = (t + 1 < NK) ? t + 1 : NK - 1;
    int k2 = (t + 2 < NK) ? t + 2 : NK - 1;
    PHASE(0, 0, true,  STAGE_A(1, bufr ^ 1, k1), false);
    PHASE(0, 1, false, STAGE_B(1, bufr ^ 1, k1), false);
    PHASE(1, 0, true,  STAGE_A(0, bufr, k2), false);
    PHASE(1, 1, false, STAGE_B(0, bufr, k2), true);
  }
  wait_vmcnt<0>();

  if (FC1) {
#pragma unroll
    for (int ng = 0; ng < N_R; ng++) {
      int NH = ng / NHF, nn = ng % NHF;
      int col = nt * BN + NH * (BN / 2) + wc * (BN / 8) + nn * 16 + l15;
      float bb = bias[(size_t)e * NTOT + col];
#pragma unroll
      for (int mg = 0; mg < 8; mg++) {
#pragma unroll
        for (int j = 0; j < 4; j++) {
          int grow = mt * BM + (mg >> 2) * 128 + wr * 64 + (mg & 3) * 16 + kc * 4 + j;
          if (grow < cnt)
            Hout[(size_t)(base + grow) * DH + col] = f2bf(gelu_tanh(acc[mg][ng][j] + bb));
        }
      }
    }
  } else {
#pragma unroll
    for (int mg = 0; mg < 8; mg++) {
#pragma unroll
      for (int j = 0; j < 4; j++) {
        int grow = mt * BM + (mg >> 2) * 128 + wr * 64 + (mg & 3) * 16 + kc * 4 + j;
        if (grow < cnt) {
          int slot = base + grow;
          int tkn = tok_map[slot];
          float w = pair_w[slot];
#pragma unroll
          for (int ng = 0; ng < N_R; ng++) {
            int NH = ng / NHF, nn = ng % NHF;
            int col = nt * BN + NH * (BN / 2) + wc * (BN / 8) + nn * 16 + l15;
            atomicAdd(&Out[(size_t)tkn * DM + col],
                      w * (acc[mg][ng][j] + bias[(size_t)e * DM + col]));
          }
        }
      }
    }
  }
#undef PHASE
#undef STAGE_A
#undef STAGE_B
}

extern "C" void kernel_launch(void* const* d_in, const int* in_sizes, int n_in,
                              void* d_out, int out_size, void* d_ws, size_t ws_size,
                              hipStream_t stream) {
  const float* x  = (const float*)d_in[0];
  const float* rw = (const float*)d_in[1];
  const float* w1 = (const float*)d_in[2];
  const float* b1 = (const float*)d_in[3];
  const float* w2 = (const float*)d_in[4];
  const float* b2 = (const float*)d_in[5];
  float* out = (float*)d_out;

  char* ws = (char*)d_ws;
  size_t off = 0;
  u16* xbf = (u16*)(ws + off); off += (size_t)T_TOK * DM * 2;
  u16* H   = (u16*)(ws + off); off += (size_t)NSLOT * DH * 2;
  u16* w1b = (u16*)(ws + off); off += WELEMS * 2;
  u16* w2b = (u16*)(ws + off); off += WELEMS * 2;
  int* tok_map  = (int*)(ws + off); off += (size_t)NSLOT * 4;
  float* pair_w = (float*)(ws + off); off += (size_t)NSLOT * 4;
  int* tok_e    = (int*)(ws + off); off += (size_t)T_TOK * 8;
  float* tok_w  = (float*)(ws + off); off += (size_t)T_TOK * 8;
  int* ctl      = (int*)(ws + off); off += 96;

  hipMemsetAsync(out, 0, (size_t)T_TOK * DM * 4, stream);
  hipMemsetAsync(ctl, 0, 24 * 4, stream);

  router_kernel<<<T_TOK / 4, 256, 0, stream>>>(x, rw, xbf, tok_e, tok_w, ctl);
  scan_kernel<<<1, 64, 0, stream>>>(ctl);
  assign_kernel<<<T_TOK / 256, 256, 0, stream>>>(tok_e, tok_w, ctl, tok_map, pair_w);
  wconv_kernel<<<8192, 256, 0, stream>>>(w1, w2, w1b, w2b);

  moe_gemm8<true, 256><<<NE * 32 * (DH / 256), 512, 0, stream>>>(
      xbf, w1b, b1, H, nullptr, tok_map, pair_w, ctl);
  moe_gemm8<false, 128><<<NE * 32 * (DM / 128), 512, 0, stream>>>(
      H, w2b, b2, nullptr, out, tok_map, pair_w, ctl);
}

// Round 5
// 562.123 us; speedup vs baseline: 1.1774x; 1.1774x over previous
//
#include <hip/hip_runtime.h>
#include <hip/hip_bf16.h>

#define T_TOK 4096
#define DM 1024
#define DH 4096
#define NE 8
#define NSLOT (T_TOK * 2)
#define WELEMS ((size_t)NE * DH * DM)

typedef __attribute__((ext_vector_type(4))) float fl4;
typedef __attribute__((ext_vector_type(8))) short sh8;
typedef __attribute__((ext_vector_type(8))) unsigned short us8;
typedef unsigned short u16;

__device__ __forceinline__ u16 f2bf(float f) {
  __hip_bfloat16 h = __float2bfloat16(f);
  return __builtin_bit_cast(u16, h);
}

__device__ __forceinline__ float gelu_tanh(float x) {
  float x3 = x * x * x;
  float u = 0.7978845608028654f * (x + 0.044715f * x3);
  return 0.5f * x * (1.0f + tanhf(u));
}

__device__ __forceinline__ void gload_lds16(const void* g, void* l) {
  __builtin_amdgcn_global_load_lds(
      (const __attribute__((address_space(1))) unsigned int*)g,
      (__attribute__((address_space(3))) unsigned int*)l, 16, 0, 0);
}

template <int N>
__device__ __forceinline__ void wait_vmcnt() {
  if constexpr (N == 0) asm volatile("s_waitcnt vmcnt(0)" ::: "memory");
  else if constexpr (N == 3) asm volatile("s_waitcnt vmcnt(3)" ::: "memory");
  else if constexpr (N == 4) asm volatile("s_waitcnt vmcnt(4)" ::: "memory");
}

// ---------------- weight fp32 -> bf16 ----------------
__global__ __launch_bounds__(256) void wconv_kernel(
    const float* __restrict__ w1, const float* __restrict__ w2,
    u16* __restrict__ w1b, u16* __restrict__ w2b) {
  size_t stride = (size_t)gridDim.x * 256 * 8;
  for (size_t i = ((size_t)blockIdx.x * 256 + threadIdx.x) * 8; i < WELEMS; i += stride) {
    fl4 a0 = *(const fl4*)(w1 + i);
    fl4 a1 = *(const fl4*)(w1 + i + 4);
    fl4 b0 = *(const fl4*)(w2 + i);
    fl4 b1 = *(const fl4*)(w2 + i + 4);
    us8 oa, ob;
#pragma unroll
    for (int j = 0; j < 4; j++) {
      oa[j] = f2bf(a0[j]); oa[j + 4] = f2bf(a1[j]);
      ob[j] = f2bf(b0[j]); ob[j + 4] = f2bf(b1[j]);
    }
    *(us8*)(w1b + i) = oa;
    *(us8*)(w2b + i) = ob;
  }
}

// ---------------- router ----------------
__global__ __launch_bounds__(256) void router_kernel(
    const float* __restrict__ x, const float* __restrict__ rw,
    u16* __restrict__ xbf, int* __restrict__ tok_e, float* __restrict__ tok_w,
    int* __restrict__ ctl) {
  int tid = threadIdx.x;
  int wv = tid >> 6, lane = tid & 63;
  int t = blockIdx.x * 4 + wv;
  if (t >= T_TOK) return;

  const float* xp = x + (size_t)t * DM + lane * 16;
  fl4 xq[4];
#pragma unroll
  for (int i = 0; i < 4; i++) xq[i] = *(const fl4*)(xp + i * 4);

  float acc8[NE];
#pragma unroll
  for (int e = 0; e < NE; e++) {
    const float* wp = rw + (size_t)e * DM + lane * 16;
    float s = 0.f;
#pragma unroll
    for (int i = 0; i < 4; i++) {
      fl4 w4 = *(const fl4*)(wp + i * 4);
      s += xq[i][0] * w4[0] + xq[i][1] * w4[1] + xq[i][2] * w4[2] + xq[i][3] * w4[3];
    }
    acc8[e] = s;
  }
  us8 h0, h1;
#pragma unroll
  for (int i = 0; i < 8; i++) {
    h0[i] = f2bf(xq[i >> 2][i & 3]);
    h1[i] = f2bf(xq[2 + (i >> 2)][i & 3]);
  }
  *(us8*)(xbf + (size_t)t * DM + lane * 16) = h0;
  *(us8*)(xbf + (size_t)t * DM + lane * 16 + 8) = h1;

#pragma unroll
  for (int e = 0; e < NE; e++) {
#pragma unroll
    for (int off = 32; off > 0; off >>= 1) acc8[e] += __shfl_xor(acc8[e], off);
  }

  if (lane == 0) {
    float v1 = -1e30f, v2 = -1e30f;
    int i1 = 0, i2 = 0;
#pragma unroll
    for (int e = 0; e < NE; e++) {
      float v = acc8[e];
      if (v > v1) { v2 = v1; i2 = i1; v1 = v; i1 = e; }
      else if (v > v2) { v2 = v; i2 = e; }
    }
    float ex = expf(v2 - v1);
    float s = 1.0f + ex;
    tok_e[t * 2] = i1; tok_e[t * 2 + 1] = i2;
    tok_w[t * 2] = 1.0f / s; tok_w[t * 2 + 1] = ex / s;
    atomicAdd(&ctl[i1], 1);
    atomicAdd(&ctl[i2], 1);
  }
}

__global__ void scan_kernel(int* __restrict__ ctl) {
  if (threadIdx.x == 0 && blockIdx.x == 0) {
    int s = 0;
    for (int e = 0; e < NE; e++) {
      int c = ctl[e];
      ctl[16 + e] = s;
      ctl[8 + e] = s;
      s += c;
    }
  }
}

__global__ __launch_bounds__(256) void assign_kernel(
    const int* __restrict__ tok_e, const float* __restrict__ tok_w,
    int* __restrict__ ctl, int* __restrict__ tok_map, float* __restrict__ pair_w,
    int* __restrict__ islot) {
  int t = blockIdx.x * 256 + threadIdx.x;
  if (t < T_TOK) {
#pragma unroll
    for (int k = 0; k < 2; k++) {
      int e = tok_e[t * 2 + k];
      int slot = atomicAdd(&ctl[8 + e], 1);
      tok_map[slot] = t;
      pair_w[slot] = tok_w[t * 2 + k];
      islot[t * 2 + k] = slot;
    }
  }
}

// ---------------- combine: out[t] = sum_k w_k * (y[slot_k] + b2[e_k]) ----------
__global__ __launch_bounds__(256) void combine_kernel(
    const float* __restrict__ y, const float* __restrict__ b2,
    const int* __restrict__ tok_e, const int* __restrict__ islot,
    const float* __restrict__ tok_w, float* __restrict__ out) {
  int idx = blockIdx.x * 256 + threadIdx.x;  // T_TOK*DM/4 lanes of fl4
  int t = idx >> 8;
  int c4 = (idx & 255) * 4;
  int e0 = tok_e[t * 2], e1 = tok_e[t * 2 + 1];
  int s0 = islot[t * 2], s1 = islot[t * 2 + 1];
  float w0 = tok_w[t * 2], w1 = tok_w[t * 2 + 1];
  fl4 y0 = *(const fl4*)(y + (size_t)s0 * DM + c4);
  fl4 y1 = *(const fl4*)(y + (size_t)s1 * DM + c4);
  fl4 bb0 = *(const fl4*)(b2 + (size_t)e0 * DM + c4);
  fl4 bb1 = *(const fl4*)(b2 + (size_t)e1 * DM + c4);
  fl4 o;
#pragma unroll
  for (int i = 0; i < 4; i++) o[i] = w0 * (y0[i] + bb0[i]) + w1 * (y1[i] + bb1[i]);
  *(fl4*)(out + (size_t)t * DM + c4) = o;
}

// ---------------- 8-phase grouped GEMM: BM=256, BK=64, 8 waves ----------------
// Round-5 changes: (1) K-loop manually unrolled 2x -> compile-time buffer
// indices; (2) 3-bit XOR swizzle: LDS(row, c) holds global chunk c^(row&7)
// (write: src chunk (lane&7)^(lane>>3); read: chunk (kk*4+kc)^(l15&7));
// (3) lgkmcnt(8) pre-drain in 12-read phases; (4) FC2 stores raw fp32 y rows
// (no bias, no atomics) for the combine kernel.
// Race-safety (unchanged from r4): phase (MH,NH) reads only A-half MH /
// B-half NH; stage targets never overlap regions read in-or-after the issuing
// phase within the live tile; counted vmcnt(VMC) once per K-tile.
template <bool FC1, int BN>
__global__ __launch_bounds__(512, 2) void moe_gemm8(
    const u16* __restrict__ Ab, const u16* __restrict__ W,
    const float* __restrict__ bias, u16* __restrict__ Hout,
    float* __restrict__ Yout, const int* __restrict__ tok_map,
    const int* __restrict__ ctl) {
  constexpr int BM = 256;
  constexpr int KTOT = FC1 ? DM : DH;
  constexpr int NTOT = FC1 ? DH : DM;
  constexpr int NT = NTOT / BN;
  constexpr int MT = NSLOT / BM;   // 32
  constexpr int NK = KTOT / 64;    // 16 (fc1) / 64 (fc2) — even
  constexpr int NHF = BN / 128;    // B frags per phase: 2 / 1
  constexpr int N_R = 2 * NHF;
  constexpr int LPH_B = BN / 128;
  constexpr int VMC = 2 + LPH_B;
  constexpr int ATS = BM * 128;
  constexpr int BTS = BN * 128;
  constexpr int BOFF = 2 * ATS;
  constexpr int NWG = NE * MT * NT;

  __shared__ char lds[2 * ATS + 2 * BTS];

  int bid = blockIdx.x;
  int swz = (bid & 7) * (NWG / 8) + (bid >> 3);
  int mt = swz % MT;
  int tmp = swz / MT;
  int nt = tmp % NT;
  int e = tmp / NT;

  int base = ctl[16 + e], cnt = ctl[e];
  if (mt * BM >= cnt) return;

  int tid = threadIdx.x;
  int wv = tid >> 6, lane = tid & 63;
  int wr = wv >> 2, wc = wv & 3;
  int l15 = lane & 15, kc = lane >> 4;
  int kb0 = (kc ^ (l15 & 7)) * 16;  // read swizzle, kk=0; kk=1 is kb0^64

  // staging source pointers (write-side inverse swizzle folded into global src)
  int c16 = (lane & 7) ^ (lane >> 3);
  const u16* aptr[2][2];
#pragma unroll
  for (int h = 0; h < 2; h++)
#pragma unroll
    for (int j = 0; j < 2; j++) {
      int rl = (wv * 2 + j) * 8 + (lane >> 3);
      int slot = base + mt * BM + h * 128 + rl;
      if (slot >= NSLOT) slot = NSLOT - 1;  // clamp: garbage rows masked on store
      size_t arow = FC1 ? (size_t)tok_map[slot] : (size_t)slot;
      aptr[h][j] = Ab + arow * KTOT + c16 * 8;
    }
  const u16* bptr[2][LPH_B];
#pragma unroll
  for (int h = 0; h < 2; h++)
#pragma unroll
    for (int j = 0; j < LPH_B; j++) {
      int rl = (wv * LPH_B + j) * 8 + (lane >> 3);
      int wrow = nt * BN + h * (BN / 2) + rl;
      bptr[h][j] = W + ((size_t)e * NTOT + wrow) * KTOT + c16 * 8;
    }

#define STAGE_A(H, BUFW, KT)                                                     \
  { _Pragma("unroll") for (int j = 0; j < 2; j++)                                \
      gload_lds16(aptr[H][j] + (KT) * 64,                                        \
                  lds + (BUFW) * ATS + (H) * (ATS / 2) + (wv * 2 + j) * 1024); }
#define STAGE_B(H, BUFW, KT)                                                     \
  { _Pragma("unroll") for (int j = 0; j < LPH_B; j++)                            \
      gload_lds16(bptr[H][j] + (KT) * 64,                                        \
                  lds + BOFF + (BUFW) * BTS + (H) * (BTS / 2) +                  \
                      (wv * LPH_B + j) * 1024); }

  fl4 acc[8][N_R];
#pragma unroll
  for (int m = 0; m < 8; m++)
#pragma unroll
    for (int n = 0; n < N_R; n++) acc[m][n] = (fl4){0.f, 0.f, 0.f, 0.f};

  sh8 afr[4][2];

#define PHASE(MH, NH, READA, STAGE_STMT, LAST, BUFR)                             \
  {                                                                              \
    if (READA) {                                                                 \
      _Pragma("unroll") for (int m = 0; m < 4; m++)                              \
      _Pragma("unroll") for (int kk = 0; kk < 2; kk++)                           \
        afr[m][kk] = *(const sh8*)(lds + (BUFR) * ATS +                          \
            (((MH) * 128 + wr * 64 + m * 16 + l15) * 128 + (kk ? (kb0 ^ 64) : kb0))); \
    }                                                                            \
    sh8 bfr[NHF][2];                                                             \
    _Pragma("unroll") for (int n = 0; n < NHF; n++)                              \
    _Pragma("unroll") for (int kk = 0; kk < 2; kk++)                             \
      bfr[n][kk] = *(const sh8*)(lds + BOFF + (BUFR) * BTS +                     \
          (((NH) * (BN / 2) + wc * (BN / 8) + n * 16 + l15) * 128 +              \
           (kk ? (kb0 ^ 64) : kb0)));                                            \
    STAGE_STMT;                                                                  \
    if (READA) asm volatile("s_waitcnt lgkmcnt(8)" ::: "memory");                \
    __builtin_amdgcn_s_barrier();                                                \
    asm volatile("s_waitcnt lgkmcnt(0)" ::: "memory");                           \
    __builtin_amdgcn_sched_barrier(0);                                           \
    __builtin_amdgcn_s_setprio(1);                                               \
    _Pragma("unroll") for (int m = 0; m < 4; m++)                                \
    _Pragma("unroll") for (int n = 0; n < NHF; n++)                              \
    _Pragma("unroll") for (int kk = 0; kk < 2; kk++)                             \
      acc[(MH) * 4 + m][(NH) * NHF + n] = __builtin_amdgcn_mfma_f32_16x16x32_bf16( \
          afr[m][kk], bfr[n][kk], acc[(MH) * 4 + m][(NH) * NHF + n], 0, 0, 0);   \
    __builtin_amdgcn_s_setprio(0);                                               \
    if (LAST) wait_vmcnt<VMC>();                                                 \
    __builtin_amdgcn_s_barrier();                                                \
  }

  // prologue: tile0 all 4 halves + tile1 A-lo/B-lo; last 2 stages stay in flight
  STAGE_A(0, 0, 0); STAGE_B(0, 0, 0);
  STAGE_A(1, 0, 0); STAGE_B(1, 0, 0);
  STAGE_A(0, 1, 1); STAGE_B(0, 1, 1);
  wait_vmcnt<VMC>();
  __builtin_amdgcn_s_barrier();

  // 2 K-tiles per iteration -> compile-time buffer indices everywhere
  for (int t = 0; t < NK; t += 2) {
    int k1 = (t + 1 < NK) ? t + 1 : NK - 1;
    int k2 = (t + 2 < NK) ? t + 2 : NK - 1;
    int k3 = (t + 3 < NK) ? t + 3 : NK - 1;
    // tile t (buf 0)
    PHASE(0, 0, true,  STAGE_A(1, 1, k1), false, 0);
    PHASE(0, 1, false, STAGE_B(1, 1, k1), false, 0);
    PHASE(1, 0, true,  STAGE_A(0, 0, k2), false, 0);
    PHASE(1, 1, false, STAGE_B(0, 0, k2), true,  0);
    // tile t+1 (buf 1)
    PHASE(0, 0, true,  STAGE_A(1, 0, k2), false, 1);
    PHASE(0, 1, false, STAGE_B(1, 0, k2), false, 1);
    PHASE(1, 0, true,  STAGE_A(0, 1, k3), false, 1);
    PHASE(1, 1, false, STAGE_B(0, 1, k3), true,  1);
  }
  wait_vmcnt<0>();

  if (FC1) {
#pragma unroll
    for (int ng = 0; ng < N_R; ng++) {
      int NH = ng / NHF, nn = ng % NHF;
      int col = nt * BN + NH * (BN / 2) + wc * (BN / 8) + nn * 16 + l15;
      float bb = bias[(size_t)e * NTOT + col];
#pragma unroll
      for (int mg = 0; mg < 8; mg++) {
#pragma unroll
        for (int j = 0; j < 4; j++) {
          int grow = mt * BM + (mg >> 2) * 128 + wr * 64 + (mg & 3) * 16 + kc * 4 + j;
          if (grow < cnt)
            Hout[(size_t)(base + grow) * DH + col] = f2bf(gelu_tanh(acc[mg][ng][j] + bb));
        }
      }
    }
  } else {
#pragma unroll
    for (int mg = 0; mg < 8; mg++) {
#pragma unroll
      for (int j = 0; j < 4; j++) {
        int grow = mt * BM + (mg >> 2) * 128 + wr * 64 + (mg & 3) * 16 + kc * 4 + j;
        if (grow < cnt) {
#pragma unroll
          for (int ng = 0; ng < N_R; ng++) {
            int NH = ng / NHF, nn = ng % NHF;
            int col = nt * BN + NH * (BN / 2) + wc * (BN / 8) + nn * 16 + l15;
            Yout[(size_t)(base + grow) * DM + col] = acc[mg][ng][j];
          }
        }
      }
    }
  }
#undef PHASE
#undef STAGE_A
#undef STAGE_B
}

extern "C" void kernel_launch(void* const* d_in, const int* in_sizes, int n_in,
                              void* d_out, int out_size, void* d_ws, size_t ws_size,
                              hipStream_t stream) {
  const float* x  = (const float*)d_in[0];
  const float* rw = (const float*)d_in[1];
  const float* w1 = (const float*)d_in[2];
  const float* b1 = (const float*)d_in[3];
  const float* w2 = (const float*)d_in[4];
  const float* b2 = (const float*)d_in[5];
  float* out = (float*)d_out;

  char* ws = (char*)d_ws;
  size_t off = 0;
  u16* xbf = (u16*)(ws + off); off += (size_t)T_TOK * DM * 2;
  u16* H   = (u16*)(ws + off); off += (size_t)NSLOT * DH * 2;
  u16* w1b = (u16*)(ws + off); off += WELEMS * 2;
  u16* w2b = (u16*)(ws + off); off += WELEMS * 2;
  int* tok_map  = (int*)(ws + off); off += (size_t)NSLOT * 4;
  float* pair_w = (float*)(ws + off); off += (size_t)NSLOT * 4;
  int* tok_e    = (int*)(ws + off); off += (size_t)T_TOK * 8;
  float* tok_w  = (float*)(ws + off); off += (size_t)T_TOK * 8;
  int* islot    = (int*)(ws + off); off += (size_t)T_TOK * 8;
  int* ctl      = (int*)(ws + off); off += 96;
  // y (fp32, 33.5 MB) overlays w1b (dead after fc1 GEMM)
  float* y = (float*)w1b;

  hipMemsetAsync(ctl, 0, 24 * 4, stream);

  router_kernel<<<T_TOK / 4, 256, 0, stream>>>(x, rw, xbf, tok_e, tok_w, ctl);
  scan_kernel<<<1, 64, 0, stream>>>(ctl);
  assign_kernel<<<T_TOK / 256, 256, 0, stream>>>(tok_e, tok_w, ctl, tok_map, pair_w, islot);
  wconv_kernel<<<8192, 256, 0, stream>>>(w1, w2, w1b, w2b);

  moe_gemm8<true, 256><<<NE * 32 * (DH / 256), 512, 0, stream>>>(
      xbf, w1b, b1, H, nullptr, tok_map, ctl);
  moe_gemm8<false, 128><<<NE * 32 * (DM / 128), 512, 0, stream>>>(
      H, w2b, nullptr, nullptr, y, tok_map, ctl);
  combine_kernel<<<T_TOK * DM / 4 / 256, 256, 0, stream>>>(
      y, b2, tok_e, islot, tok_w, out);
}